// Round 3
// baseline (184.199 us; speedup 1.0000x reference)
//
#include <hip/hip_runtime.h>
#include <stdint.h>

#define DI __device__ __forceinline__

typedef float f32x4 __attribute__((ext_vector_type(4)));
typedef short bf16x8 __attribute__((ext_vector_type(8)));

DI uint16_t f2bf(float f) {
    union { float f; uint32_t u; } v; v.f = f;
    uint32_t r = v.u + 0x7FFF + ((v.u >> 16) & 1);
    return (uint16_t)(r >> 16);
}
DI float bf2f(uint16_t h) {
    union { uint32_t u; float f; } v; v.u = ((uint32_t)h) << 16;
    return v.f;
}
// async global->LDS, 16B per lane; LDS dest = wave-uniform base + lane*16
DI void gl_lds16(const void* g, void* l) {
    __builtin_amdgcn_global_load_lds(
        (__attribute__((address_space(1))) void*)(uintptr_t)g,
        (__attribute__((address_space(3))) void*)(uintptr_t)l,
        16, 0, 0);
}

// ---------------- kernel 0: zero ce acc + Wc^T bf16 (pad 31->32) ----------
__global__ void k_init(const float* __restrict__ Wc, uint16_t* __restrict__ WcT,
                       float* __restrict__ accs) {
    int tid = threadIdx.x;
    if (tid < 4) accs[tid] = 0.f;
    for (int idx = tid; idx < 32 * 256; idx += 256) {
        int n = idx >> 8, k = idx & 255;
        WcT[idx] = (n < 31) ? f2bf(Wc[k * 31 + n]) : (uint16_t)0;
    }
}

// ---------------- kernel 1: Wb [2048][256] -> WbT bf16 [256][2048] --------
__global__ void k_transpose_wb(const float* __restrict__ Wb, uint16_t* __restrict__ WbT) {
    __shared__ float t[32][33];
    int kb = blockIdx.x, nb = blockIdx.y;
    int tx = threadIdx.x & 31, ty0 = (threadIdx.x >> 5) * 4;
    for (int i = 0; i < 4; ++i)
        t[ty0 + i][tx] = Wb[(kb * 32 + ty0 + i) * 256 + nb * 32 + tx];
    __syncthreads();
    for (int i = 0; i < 4; ++i)
        WbT[(nb * 32 + ty0 + i) * 2048 + kb * 32 + tx] = f2bf(t[tx][ty0 + i]);
}

// ---------------- kernel 2: Y = relu([src;tar] @ Wb + bb), bf16 out -------
// tile 32(m) x 64(n), BK=64, grid 1024 -> 4 blocks/CU (16 waves/CU, 4/SIMD)
// B: 3-buffer LDS ring staged 2 iters ahead; A: 2-deep register prefetch.
// One vmcnt(4) per iteration, waiting only on loads issued a full iter ago.
__launch_bounds__(256)
__global__ void k_bottleneck(const float* __restrict__ src, const float* __restrict__ tgt,
                             const uint16_t* __restrict__ WbT, const float* __restrict__ bb,
                             uint16_t* __restrict__ Y) {
    // LA[2]: 4KB @0, @4096 ; LB[3]: 8KB @8192, @16384, @24576
    __shared__ __align__(16) uint8_t lds[32768];
    int tid = threadIdx.x;
    int lane = tid & 63, w = tid >> 6;
    int bm = blockIdx.x >> 2, bn = blockIdx.x & 3;   // 4 N-slices share one A-tile
    int m0 = bm * 32;
    const float* X = (m0 < 4096) ? (src + (size_t)m0 * 2048)
                                 : (tgt + (size_t)(m0 - 4096) * 2048);
    // A-staging assignment: 8 fp32 per thread
    int ar = tid >> 3, akb = (tid >> 2) & 1, ap = tid & 3;
    int ac = ap ^ (ar & 3) ^ ((ar >> 2) & 3);
    const float* Ag = X + ar * 2048 + akb * 32 + ac * 8;
    const int AwOff = akb * 2048 + ar * 64 + ap * 16;
    int cc = (lane >> 4) ^ (lane & 3) ^ ((lane >> 2) & 3);
    // B-stage per-thread global bases (2 segments/wave of 1KB)
    const uint16_t* Bg0; const uint16_t* Bg1;
    int lb0, lb1;   // LDS seg offsets within a B buffer
    {
        int p = lane & 3;
        #define BGADDR(ii) ({ int s_ = w * 2 + (ii); int kb_ = s_ >> 2; \
            int r_ = (s_ & 3) * 16 + (lane >> 2); \
            int c_ = p ^ (r_ & 3) ^ ((r_ >> 2) & 3); \
            WbT + (size_t)(bn * 64 + r_) * 2048 + kb_ * 32 + c_ * 8; })
        Bg0 = BGADDR(0); Bg1 = BGADDR(1);
        #undef BGADDR
        lb0 = (w * 2 + 0) * 1024;
        lb1 = (w * 2 + 1) * 1024;
    }
    int rnOff = (w * 16 + (lane & 15)) * 64 + cc * 16;   // B fragment row offset

    f32x4 acc[2] = {};
    float4 rE0, rE1, rO0, rO1;

    #define STAGE_B(buf, k0) do { \
        gl_lds16(Bg0 + (k0), lds + 8192 + (buf) * 8192 + lb0); \
        gl_lds16(Bg1 + (k0), lds + 8192 + (buf) * 8192 + lb1); \
    } while (0)

    #define WRITE_A(par, r0v, r1v) do { \
        uint4 u_; \
        u_.x = (uint32_t)f2bf((r0v).x) | ((uint32_t)f2bf((r0v).y) << 16); \
        u_.y = (uint32_t)f2bf((r0v).z) | ((uint32_t)f2bf((r0v).w) << 16); \
        u_.z = (uint32_t)f2bf((r1v).x) | ((uint32_t)f2bf((r1v).y) << 16); \
        u_.w = (uint32_t)f2bf((r1v).z) | ((uint32_t)f2bf((r1v).w) << 16); \
        *(uint4*)(lds + (par) * 4096 + AwOff) = u_; \
    } while (0)

    #define COMPUTE(buf, par) do { \
        _Pragma("unroll") \
        for (int kb = 0; kb < 2; ++kb) { \
            bf16x8 a_[2], b_; \
            _Pragma("unroll") \
            for (int mi = 0; mi < 2; ++mi) \
                a_[mi] = *(const bf16x8*)(lds + (par) * 4096 + kb * 2048 + \
                                          (mi * 16 + (lane & 15)) * 64 + cc * 16); \
            b_ = *(const bf16x8*)(lds + 8192 + (buf) * 8192 + kb * 4096 + rnOff); \
            _Pragma("unroll") \
            for (int mi = 0; mi < 2; ++mi) \
                acc[mi] = __builtin_amdgcn_mfma_f32_16x16x32_bf16( \
                    a_[mi], b_, acc[mi], 0, 0, 0); \
        } \
    } while (0)

    #define FENCE() asm volatile("" ::: "memory")
    #define WAIT4() asm volatile("s_waitcnt vmcnt(4)" ::: "memory")
    #define WAIT0() asm volatile("s_waitcnt vmcnt(0)" ::: "memory")
    #define LGKM0_BAR() do { asm volatile("s_waitcnt lgkmcnt(0)" ::: "memory"); \
                             __builtin_amdgcn_s_barrier(); } while (0)

    // ---- prologue ----
    STAGE_B(0, 0);                                   // B0 [2]
    FENCE();
    rE0 = *(const float4*)(Ag);                      // A0 [2]
    rE1 = *(const float4*)(Ag + 4);
    FENCE();
    STAGE_B(1, 64);                                  // B1 [2]
    FENCE();
    rO0 = *(const float4*)(Ag + 64);                 // A1 [2]  queue=8
    rO1 = *(const float4*)(Ag + 68);
    WAIT4();                                         // B0+A0 done; B1,A1 in flight
    WRITE_A(0, rE0, rE1);
    LGKM0_BAR();

    // ---- main loop: t = 0..29, 6-unrolled (ring%3 x parity%2) ----
    // invariant at iter t entry: outstanding = B(t+1)[2], A(t+1)[2]
    #define ITER(tc, BUF, NBUF, RL0, RL1, RW0, RW1, WPAR) do { \
        STAGE_B(NBUF, ((tc) + 2) * 64); \
        FENCE(); \
        RL0 = *(const float4*)(Ag + ((tc) + 2) * 64); \
        RL1 = *(const float4*)(Ag + ((tc) + 2) * 64 + 4); \
        FENCE(); \
        COMPUTE(BUF, (tc) & 1); \
        WAIT4(); /* drains B(t+1)+A(t+1); leaves B(t+2)+A(t+2) */ \
        WRITE_A(WPAR, RW0, RW1); \
        LGKM0_BAR(); \
    } while (0)

    for (int t6 = 0; t6 < 5; ++t6) {
        int tb = t6 * 6;
        ITER(tb + 0, 0, 2, rE0, rE1, rO0, rO1, 1);
        ITER(tb + 1, 1, 0, rO0, rO1, rE0, rE1, 0);
        ITER(tb + 2, 2, 1, rE0, rE1, rO0, rO1, 1);
        ITER(tb + 3, 0, 2, rO0, rO1, rE0, rE1, 0);
        ITER(tb + 4, 1, 0, rE0, rE1, rO0, rO1, 1);
        ITER(tb + 5, 2, 1, rO0, rO1, rE0, rE1, 0);
    }
    // ---- tail t=30: no new issues; outstanding = B31,A31 ----
    COMPUTE(0, 0);
    WAIT0();
    WRITE_A(1, rO0, rO1);
    LGKM0_BAR();
    // ---- t=31 ----
    COMPUTE(1, 1);

    #undef ITER
    #undef STAGE_B
    #undef WRITE_A
    #undef COMPUTE
    #undef FENCE
    #undef WAIT4
    #undef WAIT0
    #undef LGKM0_BAR

    {
        int col = bn * 64 + w * 16 + (lane & 15);
        float bias = bb[col];
        for (int mi = 0; mi < 2; ++mi) {
            for (int j = 0; j < 4; ++j) {
                int row = m0 + mi * 16 + (lane >> 4) * 4 + j;
                float v = acc[mi][j] + bias;
                v = fmaxf(v, 0.f);
                Y[(size_t)row * 256 + col] = f2bf(v);
            }
        }
    }
}

// ---------------- kernel 3: fused row sum-of-squares + column partials ----
// single pass over Y; grid 256 blocks x 32 rows; colsum_part is [256][256]
__launch_bounds__(256)
__global__ void k_stats(const uint16_t* __restrict__ Y, float* __restrict__ s2t2,
                        float* __restrict__ colsum_part) {
    __shared__ float cs[4][256];
    int tid = threadIdx.x, lane = tid & 63, w = tid >> 6;
    int r0 = blockIdx.x * 32 + w * 8;
    float c0 = 0.f, c1 = 0.f, c2 = 0.f, c3 = 0.f;
    for (int i = 0; i < 8; ++i) {
        int row = r0 + i;
        ushort4 v = *(const ushort4*)(Y + (size_t)row * 256 + lane * 4);
        float a = bf2f(v.x), b = bf2f(v.y), c = bf2f(v.z), d = bf2f(v.w);
        c0 += a; c1 += b; c2 += c; c3 += d;
        float s = a * a + b * b + c * c + d * d;
        for (int m = 1; m < 64; m <<= 1) s += __shfl_xor(s, m);
        if (lane == 0) s2t2[row] = s;
    }
    cs[w][lane * 4 + 0] = c0;
    cs[w][lane * 4 + 1] = c1;
    cs[w][lane * 4 + 2] = c2;
    cs[w][lane * 4 + 3] = c3;
    __syncthreads();
    colsum_part[blockIdx.x * 256 + tid] =
        cs[0][tid] + cs[1][tid] + cs[2][tid] + cs[3][tid];
}

// ---------------- kernel 5: classifier + softmax margins + CE -----------
__launch_bounds__(256)
__global__ void k_classifier(const uint16_t* __restrict__ Y, const uint16_t* __restrict__ WcT,
                             const float* __restrict__ bc, const int* __restrict__ labels,
                             float* __restrict__ out_margin, float* __restrict__ ce_acc) {
    __shared__ __align__(16) uint8_t lds[49152];  // A 32KB @0, B 16KB @32768
    int tid = threadIdx.x, lane = tid & 63, w = tid >> 6;
    int m0 = blockIdx.x * 64;
    int cc = (lane >> 4) ^ (lane & 3) ^ ((lane >> 2) & 3);
    for (int s = w; s < 48; s += 4) {
        int r, p, c;
        if (s < 32) {
            int kb = s >> 2, r0 = (s & 3) * 16;
            r = r0 + (lane >> 2); p = lane & 3;
            c = p ^ (r & 3) ^ ((r >> 2) & 3);
            gl_lds16(Y + (size_t)(m0 + r) * 256 + kb * 32 + c * 8, lds + s * 1024);
        } else {
            int s2 = s - 32;
            int kb = s2 >> 1, r0 = (s2 & 1) * 16;
            r = r0 + (lane >> 2); p = lane & 3;
            c = p ^ (r & 3) ^ ((r >> 2) & 3);
            gl_lds16(WcT + r * 256 + kb * 32 + c * 8, lds + 32768 + s2 * 1024);
        }
    }
    __syncthreads();
    f32x4 acc[2] = {};
    for (int kb = 0; kb < 8; ++kb) {
        int r = w * 16 + (lane & 15);
        bf16x8 a = *(const bf16x8*)(lds + kb * 4096 + r * 64 + cc * 16);
        for (int nf = 0; nf < 2; ++nf) {
            int rn = nf * 16 + (lane & 15);
            bf16x8 b = *(const bf16x8*)(lds + 32768 + kb * 2048 + rn * 64 + cc * 16);
            acc[nf] = __builtin_amdgcn_mfma_f32_16x16x32_bf16(a, b, acc[nf], 0, 0, 0);
        }
    }
    int c0 = lane & 15, c1 = 16 + c0;
    float bc0 = bc[c0];
    float bc1 = (c1 < 31) ? bc[c1] : 0.f;
    bool is_src = (m0 < 4096);
    float ce_local = 0.f;
    for (int j = 0; j < 4; ++j) {
        int row = m0 + w * 16 + (lane >> 4) * 4 + j;
        float v0 = acc[0][j] + bc0;
        float v1 = (c1 < 31) ? (acc[1][j] + bc1) : -1e30f;
        float mx = fmaxf(v0, v1);
        for (int m = 1; m < 16; m <<= 1) mx = fmaxf(mx, __shfl_xor(mx, m, 16));
        float e0 = __expf(v0 - mx);
        float e1 = (c1 < 31) ? __expf(v1 - mx) : 0.f;
        float ssum = e0 + e1;
        for (int m = 1; m < 16; m <<= 1) ssum += __shfl_xor(ssum, m, 16);
        float inv = 1.f / ssum;
        float conf0 = e0 * inv, conf1 = e1 * inv;
        int lab;
        if (is_src) {
            lab = labels[row];
        } else {
            float bv; int bi;
            if (v0 >= v1) { bv = v0; bi = c0; } else { bv = v1; bi = c1; }
            for (int m = 1; m < 16; m <<= 1) {
                float ov = __shfl_xor(bv, m, 16);
                int oi = __shfl_xor(bi, m, 16);
                if (ov > bv || (ov == bv && oi < bi)) { bv = ov; bi = oi; }
            }
            lab = bi;
        }
        float tc = (c0 == lab ? conf0 : 0.f) + (c1 == lab ? conf1 : 0.f);
        for (int m = 1; m < 16; m <<= 1) tc += __shfl_xor(tc, m, 16);
        float ex = fmaxf(c0 == lab ? -1.f : conf0,
                         (c1 == lab || c1 >= 31) ? -1.f : conf1);
        for (int m = 1; m < 16; m <<= 1) ex = fmaxf(ex, __shfl_xor(ex, m, 16));
        if (c0 == 0) out_margin[row] = tc - ex;
        if (is_src) {
            float vl = (c0 == lab) ? v0 : ((c1 == lab) ? v1 : -1e30f);
            for (int m = 1; m < 16; m <<= 1) vl = fmaxf(vl, __shfl_xor(vl, m, 16));
            if (c0 == 0) ce_local += -(vl - mx - __logf(ssum));
        }
    }
    if (is_src) {
        ce_local += __shfl_xor(ce_local, 16);
        ce_local += __shfl_xor(ce_local, 32);
        if (lane == 0) atomicAdd(ce_acc, ce_local);   // 64 atomics total: fine
    }
}

// ---------------- kernel 6: pairwise d2 -> exp partial sums (no atomics) -
// 128x128 tile, K=256 staged in 2 halves of 64KB LDS
__launch_bounds__(256)
__global__ void k_pairwise(const uint16_t* __restrict__ Y, const float* __restrict__ s2t2,
                           float* __restrict__ gk_part) {
    __shared__ __align__(16) uint8_t lds[65536];  // A 32KB @0, B 32KB @32768
    int tid = threadIdx.x, lane = tid & 63, w = tid >> 6;
    int m0 = blockIdx.x * 128, n0 = blockIdx.y * 128;
    int cc = (lane >> 4) ^ (lane & 3) ^ ((lane >> 2) & 3);
    int wm = (w & 1) * 64, wn = (w >> 1) * 64;
    f32x4 acc[4][4] = {};
    for (int h = 0; h < 2; ++h) {
        if (h) __syncthreads();
        int k0 = h * 128;
        for (int i = 0; i < 8; ++i) {
            int s = w * 8 + i;
            int kb = s >> 3, r0 = (s & 7) * 16;
            int r = r0 + (lane >> 2), p = lane & 3;
            int c = p ^ (r & 3) ^ ((r >> 2) & 3);
            gl_lds16(Y + (size_t)(m0 + r) * 256 + k0 + kb * 32 + c * 8, lds + s * 1024);
            gl_lds16(Y + (size_t)(4096 + n0 + r) * 256 + k0 + kb * 32 + c * 8,
                     lds + 32768 + s * 1024);
        }
        __syncthreads();
        for (int kb = 0; kb < 4; ++kb) {
            bf16x8 a[4], b[4];
            for (int mi = 0; mi < 4; ++mi) {
                int r = wm + mi * 16 + (lane & 15);
                a[mi] = *(const bf16x8*)(lds + kb * 8192 + r * 64 + cc * 16);
            }
            for (int nf = 0; nf < 4; ++nf) {
                int rn = wn + nf * 16 + (lane & 15);
                b[nf] = *(const bf16x8*)(lds + 32768 + kb * 8192 + rn * 64 + cc * 16);
            }
            for (int mi = 0; mi < 4; ++mi)
                for (int nf = 0; nf < 4; ++nf)
                    acc[mi][nf] = __builtin_amdgcn_mfma_f32_16x16x32_bf16(
                        a[mi], b[nf], acc[mi][nf], 0, 0, 0);
        }
    }
    float t2v[4];
    for (int nf = 0; nf < 4; ++nf)
        t2v[nf] = s2t2[4096 + n0 + wn + nf * 16 + (lane & 15)];
    float g1 = 0.f, g5 = 0.f;
    for (int mi = 0; mi < 4; ++mi) {
        int rbase = m0 + wm + mi * 16 + (lane >> 4) * 4;
        float s2v[4];
        for (int j = 0; j < 4; ++j) s2v[j] = s2t2[rbase + j];
        for (int nf = 0; nf < 4; ++nf)
            for (int j = 0; j < 4; ++j) {
                float d2 = s2v[j] + t2v[nf] - 2.f * acc[mi][nf][j];
                d2 = fmaxf(d2, 0.f);
                g1 += __expf(-0.5f * d2);
                g5 += __expf(-0.02f * d2);
            }
    }
    for (int m = 1; m < 64; m <<= 1) { g1 += __shfl_xor(g1, m); g5 += __shfl_xor(g5, m); }
    // block-level reduce (reuse LDS), one plain store per block
    __syncthreads();
    float* red = (float*)lds;
    if (lane == 0) { red[w * 2] = g1; red[w * 2 + 1] = g5; }
    __syncthreads();
    if (tid == 0) {
        int bid = blockIdx.y * 32 + blockIdx.x;
        gk_part[bid * 2]     = red[0] + red[2] + red[4] + red[6];
        gk_part[bid * 2 + 1] = red[1] + red[3] + red[5] + red[7];
    }
}

// ---------------- kernel 7: finalize scalars ----------------------------
__global__ void k_finalize(const float* __restrict__ colsum_part,
                           const float* __restrict__ gk_part,
                           const float* __restrict__ accs, float* __restrict__ d_out) {
    __shared__ float red[12];
    int tid = threadIdx.x, lane = tid & 63, w = tid >> 6;
    float cs = 0.f, ct = 0.f;
    for (int b = 0; b < 128; ++b)   cs += colsum_part[b * 256 + tid];
    for (int b = 128; b < 256; ++b) ct += colsum_part[b * 256 + tid];
    float delta = (cs - ct) * (1.f / 4096.f);
    float sq = delta * delta;
    float g1 = 0.f, g5 = 0.f;
    for (int i = 0; i < 4; ++i) {
        int p = tid * 4 + i;
        g1 += gk_part[p * 2];
        g5 += gk_part[p * 2 + 1];
    }
    for (int m = 1; m < 64; m <<= 1) {
        sq += __shfl_xor(sq, m);
        g1 += __shfl_xor(g1, m);
        g5 += __shfl_xor(g5, m);
    }
    if (lane == 0) { red[w * 3] = sq; red[w * 3 + 1] = g1; red[w * 3 + 2] = g5; }
    __syncthreads();
    if (tid == 0) {
        d_out[0] = accs[0] * (1.f / 4096.f);
        d_out[1] = red[0] + red[3] + red[6] + red[9];
        d_out[2] = (red[1] + red[4] + red[7] + red[10]) * 5.9604644775390625e-08f;
        d_out[3] = (red[2] + red[5] + red[8] + red[11]) * 5.9604644775390625e-08f;
    }
}

extern "C" void kernel_launch(void* const* d_in, const int* in_sizes, int n_in,
                              void* d_out, int out_size, void* d_ws, size_t ws_size,
                              hipStream_t stream) {
    const float* source = (const float*)d_in[0];
    const float* target = (const float*)d_in[1];
    const float* Wb     = (const float*)d_in[2];
    const float* bb     = (const float*)d_in[3];
    const float* Wc     = (const float*)d_in[4];
    const float* bc     = (const float*)d_in[5];
    const int*   labels = (const int*)d_in[6];
    float* out = (float*)d_out;
    uint8_t* ws = (uint8_t*)d_ws;

    uint16_t* Y    = (uint16_t*)(ws);                 // 8192*256*2 = 4 MB
    uint16_t* WbT  = (uint16_t*)(ws + 4194304);       // 1 MB (dead after k_bottleneck)
    uint16_t* WcT  = (uint16_t*)(ws + 5242880);       // 16 KB
    float*    s2t2 = (float*)(ws + 5259264);          // 32 KB
    float*    accs = (float*)(ws + 5292032);          // [ce, pad...]
    // alias the dead WbT region (only read by k_bottleneck, which runs first):
    float*    colsum_part = (float*)(ws + 4194304);             // 256*256 fl = 256 KB
    float*    gk_part     = (float*)(ws + 4194304 + 262144);    // 1024*2 fl = 8 KB

    k_init<<<1, 256, 0, stream>>>(Wc, WcT, accs);
    k_transpose_wb<<<dim3(64, 8), 256, 0, stream>>>(Wb, WbT);
    k_bottleneck<<<1024, 256, 0, stream>>>(source, target, WbT, bb, Y);
    k_stats<<<256, 256, 0, stream>>>(Y, s2t2, colsum_part);
    k_classifier<<<128, 256, 0, stream>>>(Y, WcT, bc, labels, out + 4, accs);
    k_pairwise<<<dim3(32, 32), 256, 0, stream>>>(Y, s2t2, gk_part);
    k_finalize<<<1, 256, 0, stream>>>(colsum_part, gk_part, accs, out);
}